// Round 4
// baseline (243.460 us; speedup 1.0000x reference)
//
#include <hip/hip_runtime.h>

// SparseMSDeformableAttention MI355X — round 12.
// r11 post-mortem: sample won (-11us, conflicts 0) but GEMM B-once/A-dbuf LOST
// +11us: 48KB LDS -> 3 blocks/CU killed the TLP that was hiding the per-step
// vmcnt0 drain (m132 lesson). sample_k FETCH=111MB = 8 XCDs x whole 13.6MB vproj:
// every gather L2-misses (random loc > 4MB L2); per-HEAD slice is 1.7MB = L2-fit.
//  - gemm_tile: reverted to r10 body (12KB LDS, 3 gll/k-step, 2 barriers, 8 blk/CU).
//  - sample_k: head-pinned blocks (head = bid&7 = XCD via round-robin dispatch) ->
//    per-XCD gather working set 1.7MB L2-resident. No-LDS rewrite: wave=(tok,head),
//    lane=point(16)x chgrp(4); softmax via shfl_xor(4,8,16,32); in-reg weights;
//    4 gathers/lane; shfl_down(32,16,8,4) point-reduce; lanes p==0 store 16B.

#define LQ    13294
#define NTOK  26588
#define NE    6806528     // NTOK*256

typedef unsigned short ushort_t;
typedef __attribute__((ext_vector_type(8))) short short8;
typedef __attribute__((ext_vector_type(8))) unsigned short ushort8_t;
typedef __attribute__((ext_vector_type(4))) float float4_t;

__device__ __forceinline__ ushort_t f2b(float f) {
    unsigned int x = __float_as_uint(f);
    return (ushort_t)((x + 0x7fffu + ((x >> 16) & 1u)) >> 16);   // RNE
}

__device__ __forceinline__ void gload16(const void* g, void* l) {
    __builtin_amdgcn_global_load_lds(
        (const __attribute__((address_space(1))) unsigned int*)g,
        (__attribute__((address_space(3))) unsigned int*)l, 16, 0, 0);
}

// ---------------- bulk f32 -> bf16 convert ----------------
__device__ __forceinline__ void cvt_seg(const float* __restrict__ s,
                                        ushort_t* __restrict__ d,
                                        int n4, int gid, int stride) {
    const float4_t* s4 = (const float4_t*)s;
    for (int i = gid; i < n4; i += stride) {
        float4_t f = s4[i];
        ushort4 o;
        o.x = f2b(f.x); o.y = f2b(f.y); o.z = f2b(f.z); o.w = f2b(f.w);
        *(ushort4*)(d + (long)i * 4) = o;
    }
}

__global__ __launch_bounds__(256) void cvt_k(
    const float* q, const float* v, const float* Wv, const float* Wo,
    const float* Wa, const float* Wout,
    ushort_t* q_bf, ushort_t* v_bf, ushort_t* Wv_bf, ushort_t* WoWa_bf,
    ushort_t* Wout_bf)
{
    const int gid = blockIdx.x * 256 + threadIdx.x;
    const int stride = gridDim.x * 256;
    cvt_seg(q,    q_bf,            NE / 4,     gid, stride);
    cvt_seg(v,    v_bf,            NE / 4,     gid, stride);
    cvt_seg(Wv,   Wv_bf,           65536 / 4,  gid, stride);
    cvt_seg(Wo,   WoWa_bf,         65536 / 4,  gid, stride);   // rows 0..255
    cvt_seg(Wa,   WoWa_bf + 65536, 32768 / 4,  gid, stride);   // rows 256..383
    cvt_seg(Wout, Wout_bf,         65536 / 4,  gid, stride);
}

// ---------------- bf16 MFMA tile body (r10 structure: 12KB LDS, high TLP) ------
// 256 threads = 4 waves; tile 128(M) x 64(N), K-tile 32; LDS linear stride 32.
// Per k-step: 2 A-gll + 1 B-gll per wave (16 rows x 64B; lane l writes
// lds_base + l*16 = exactly linear). Frag maps (r7-validated):
// A[m=ln&15][k=(ln>>4)*8+j]; B=W[n=ln&15][k]; D col=ln&15, row=(ln>>4)*4+r.
__device__ __forceinline__ void gemm_tile(
    const ushort_t* __restrict__ A,     // [>=m0+128][256] bf16 (OOB rows ok: ws)
    const ushort_t* __restrict__ W,     // [>=n0+64][256] bf16
    int m0, int n0,
    ushort_t* As, ushort_t* Bs, float4_t acc[2][4])
{
    const int tid = threadIdx.x;
    const int w  = tid >> 6;
    const int ln = tid & 63;
    const int lr = ln >> 2;             // row 0..15 within 16-row group
    const int lc = (ln & 3) * 8;        // ushort col {0,8,16,24}

    ushort_t* lA0 = As + (w * 2 + 0) * 512;         // rows w*32 + 0..15
    ushort_t* lA1 = As + (w * 2 + 1) * 512;         // rows w*32 + 16..31
    ushort_t* lB  = Bs + w * 512;                   // rows w*16 + 0..15
    const ushort_t* gA0 = A + (long)(m0 + w * 32 + lr) * 256 + lc;
    const ushort_t* gA1 = gA0 + 16 * 256;
    const ushort_t* gB  = W + (long)(n0 + w * 16 + lr) * 256 + lc;

    const int krow = (ln >> 4) * 8;
    const int fr   = ln & 15;

    for (int k0 = 0; k0 < 256; k0 += 32) {
        gload16(gA0 + k0, lA0);
        gload16(gA1 + k0, lA1);
        gload16(gB  + k0, lB);
        __syncthreads();

        short8 af[2], bfr[4];
        #pragma unroll
        for (int i = 0; i < 2; i++)
            af[i] = *(const short8*)(As + (w * 32 + i * 16 + fr) * 32 + krow);
        #pragma unroll
        for (int j = 0; j < 4; j++)
            bfr[j] = *(const short8*)(Bs + (j * 16 + fr) * 32 + krow);
        #pragma unroll
        for (int i = 0; i < 2; i++)
            #pragma unroll
            for (int j = 0; j < 4; j++)
                acc[i][j] = __builtin_amdgcn_mfma_f32_16x16x32_bf16(af[i], bfr[j], acc[i][j], 0, 0, 0);
        __syncthreads();
    }
}

// ---------------- fused gemm1 (z=0) + gemm2/3 (z=1) ----------------
// z=0: vproj(bf16,*zeta, HEAD-MAJOR [8][NTOK][32]) = v_bf @ Wv^T + b_value
// z=1: oa(f32)[NTOK][384] = q_bf @ [Wo;Wa]^T + [b_off;b_attn]
__global__ __launch_bounds__(256) void gemm_fused_k(
    const ushort_t* __restrict__ q_bf, const ushort_t* __restrict__ v_bf,
    const ushort_t* __restrict__ Wv,   const ushort_t* __restrict__ WoWa,
    const float* __restrict__ b_value, const float* __restrict__ b_off,
    const float* __restrict__ b_attn,  const float* __restrict__ zeta,
    ushort_t* __restrict__ vproj, float* __restrict__ oa)
{
    __shared__ __align__(16) ushort_t As[128 * 32];
    __shared__ __align__(16) ushort_t Bs[64 * 32];

    const int z = blockIdx.z;
    const int bid = blockIdx.x;
    int x, y;
    if (z == 0) {
        if (bid >= 832) return;                 // whole block, before any barrier
        int id = (bid & 7) * 104 + (bid >> 3);  // 832 = 8*104, bijective
        x = id >> 2; y = id & 3;
    } else {
        int id = (bid & 7) * 156 + (bid >> 3);  // 1248 = 8*156, bijective
        x = id / 6; y = id - x * 6;
    }
    const int m0 = x * 128;
    const int n0 = y * 64;

    float4_t acc[2][4] = {};
    gemm_tile(z ? q_bf : v_bf, z ? WoWa : Wv, m0, n0, As, Bs, acc);

    const int tid = threadIdx.x;
    const int w = tid >> 6, ln = tid & 63;
    const int col = ln & 15;
    const int rq  = (ln >> 4) * 4;
    #pragma unroll
    for (int j = 0; j < 4; j++) {
        int n = n0 + j * 16 + col;
        if (z == 0) {
            float bz = b_value[n];
            float zz = zeta[n & 31];
            long hbase = (long)(n >> 5) * NTOK;
            #pragma unroll
            for (int i = 0; i < 2; i++) {
                #pragma unroll
                for (int r = 0; r < 4; r++) {
                    int m = m0 + w * 32 + i * 16 + rq + r;
                    if (m < NTOK)
                        vproj[(hbase + m) * 32 + (n & 31)] = f2b((acc[i][j][r] + bz) * zz);
                }
            }
        } else {
            float bz = (n < 256) ? b_off[n] : b_attn[n - 256];
            #pragma unroll
            for (int i = 0; i < 2; i++) {
                #pragma unroll
                for (int r = 0; r < 4; r++) {
                    int m = m0 + w * 32 + i * 16 + rq + r;
                    if (m < NTOK) oa[(long)m * 384 + n] = acc[i][j][r] + bz;
                }
            }
        }
    }
}

// ---------------- final out-projection gemm (f32 out) ----------------
__global__ __launch_bounds__(256) void gemm_out_k(
    const ushort_t* __restrict__ A,     // outpre [NTOK][256] bf16
    const ushort_t* __restrict__ W,     // Wout_bf [256][256]
    const float* __restrict__ bias,     // [256]
    float* __restrict__ C)              // [NTOK][256] f32
{
    __shared__ __align__(16) ushort_t As[128 * 32];
    __shared__ __align__(16) ushort_t Bs[64 * 32];

    const int bid = blockIdx.x;                 // 832
    int id = (bid & 7) * 104 + (bid >> 3);
    const int m0 = (id >> 2) * 128;
    const int n0 = (id & 3) * 64;

    float4_t acc[2][4] = {};
    gemm_tile(A, W, m0, n0, As, Bs, acc);

    const int tid = threadIdx.x;
    const int w = tid >> 6, ln = tid & 63;
    const int col = ln & 15;
    const int rq  = (ln >> 4) * 4;
    #pragma unroll
    for (int j = 0; j < 4; j++) {
        int n = n0 + j * 16 + col;
        float bz = bias[n];
        #pragma unroll
        for (int i = 0; i < 2; i++) {
            #pragma unroll
            for (int r = 0; r < 4; r++) {
                int m = m0 + w * 32 + i * 16 + rq + r;
                if (m < NTOK) C[(long)m * 256 + n] = acc[i][j][r] + bz;
            }
        }
    }
}

// ---------------- sampler: head-pinned, no LDS ----------------
// head = bid&7 = XCD (round-robin dispatch): per-XCD gather set = one head slice
// of vproj = 1.7MB -> L2-resident. Wave = (token, head); lane = p(16) x g(4).
// Softmax over 16 pts via shfl_xor; weights in-reg; 4x 16B gathers/lane;
// point-reduce via shfl_down; lanes p==0 (ln 0..3) store 16B each.
__global__ __launch_bounds__(512) void sample_k(
    const float* __restrict__ refp,    // [NTOK][4][2]
    const ushort_t* __restrict__ v,    // [8][NTOK][32] bf16 head-major
    const float* __restrict__ oa,      // [NTOK][384]: 256 off then 128 logits
    ushort_t* __restrict__ outp)       // [NTOK][256] bf16
{
    const int bid = blockIdx.x;
    const int h   = bid & 7;                         // head == XCD
    const int tid = threadIdx.x;
    const long t  = (long)(bid >> 3) * 8 + (tid >> 6);
    if (t >= NTOK) return;                           // wave-uniform, no barriers
    const int b  = (t >= LQ) ? 1 : 0;
    const int ln = tid & 63;
    const int p  = ln >> 2, g = ln & 3;
    const int lvl = p >> 2;
    const int Wi  = (lvl == 0) ? 100 : (lvl == 1) ? 50 : (lvl == 2) ? 25 : 13;
    const int st  = (lvl == 0) ? 0 : (lvl == 1) ? 10000 : (lvl == 2) ? 12500 : 13125;
    const float Wf = (float)Wi;

    // softmax over the head's 16 points (lanes differ in p at bits 2..5)
    float lg = oa[t * 384 + 256 + h * 16 + p];
    float smax = lg;
    #pragma unroll
    for (int d = 4; d < 64; d <<= 1) smax = fmaxf(smax, __shfl_xor(smax, d, 64));
    float ex = __expf(lg - smax);
    float sm = ex;
    #pragma unroll
    for (int d = 4; d < 64; d <<= 1) sm += __shfl_xor(sm, d, 64);
    const float a = ex / sm;

    float ox = oa[t * 384 + h * 32 + p * 2];
    float oy = oa[t * 384 + h * 32 + p * 2 + 1];
    float rx = refp[t * 8 + lvl * 2];
    float ry = refp[t * 8 + lvl * 2 + 1];

    float x = rx * Wf + ox - 0.5f;
    float y = ry * Wf + oy - 0.5f;
    float xf = floorf(x), yf = floorf(y);
    float wx = x - xf, wy = y - yf;
    int x0 = (int)xf, y0 = (int)yf;

    float mx0 = ((unsigned)x0       < (unsigned)Wi) ? (1.f - wx) : 0.f;
    float mx1 = ((unsigned)(x0 + 1) < (unsigned)Wi) ? wx         : 0.f;
    float my0 = ((unsigned)y0       < (unsigned)Wi) ? (1.f - wy) * a : 0.f;
    float my1 = ((unsigned)(y0 + 1) < (unsigned)Wi) ? wy * a         : 0.f;
    int x0c = min(max(x0, 0), Wi - 1);
    int x1c = min(max(x0 + 1, 0), Wi - 1);
    int y0c = min(max(y0, 0), Wi - 1);
    int y1c = min(max(y0 + 1, 0), Wi - 1);

    const int hb = h * NTOK + b * LQ + st;           // row index in [8*NTOK][32]
    const int go = g * 16;                           // byte offset within 64B row
    const int r0 = hb + y0c * Wi, r1 = hb + y1c * Wi;
    const char* vb = (const char*)v;
    uint4 u00 = *(const uint4*)(vb + (((r0 + x0c) << 6) + go));
    uint4 u01 = *(const uint4*)(vb + (((r0 + x1c) << 6) + go));
    uint4 u10 = *(const uint4*)(vb + (((r1 + x0c) << 6) + go));
    uint4 u11 = *(const uint4*)(vb + (((r1 + x1c) << 6) + go));

    const float w00 = mx0 * my0, w01 = mx1 * my0;
    const float w10 = mx0 * my1, w11 = mx1 * my1;

    float4_t accA = {0.f, 0.f, 0.f, 0.f};
    float4_t accB = {0.f, 0.f, 0.f, 0.f};
    #define ACC8(U, WGT) \
        accA[0] += (WGT) * __uint_as_float((U).x << 16); \
        accA[1] += (WGT) * __uint_as_float((U).x & 0xffff0000u); \
        accA[2] += (WGT) * __uint_as_float((U).y << 16); \
        accA[3] += (WGT) * __uint_as_float((U).y & 0xffff0000u); \
        accB[0] += (WGT) * __uint_as_float((U).z << 16); \
        accB[1] += (WGT) * __uint_as_float((U).z & 0xffff0000u); \
        accB[2] += (WGT) * __uint_as_float((U).w << 16); \
        accB[3] += (WGT) * __uint_as_float((U).w & 0xffff0000u);
    ACC8(u00, w00)
    ACC8(u01, w01)
    ACC8(u10, w10)
    ACC8(u11, w11)
    #undef ACC8

    // reduce over the 16 point-lanes (stride 4)
    #pragma unroll
    for (int d = 32; d >= 4; d >>= 1) {
        #pragma unroll
        for (int c = 0; c < 4; c++) {
            accA[c] += __shfl_down(accA[c], d, 64);
            accB[c] += __shfl_down(accB[c], d, 64);
        }
    }

    if (p == 0) {                                    // lanes 0..3 (g = ln)
        ushort8_t o8;
        o8[0] = f2b(accA[0]); o8[1] = f2b(accA[1]);
        o8[2] = f2b(accA[2]); o8[3] = f2b(accA[3]);
        o8[4] = f2b(accB[0]); o8[5] = f2b(accB[1]);
        o8[6] = f2b(accB[2]); o8[7] = f2b(accB[3]);
        *(ushort8_t*)(outp + t * 256 + h * 32 + g * 8) = o8;
    }
}

extern "C" void kernel_launch(void* const* d_in, const int* in_sizes, int n_in,
                              void* d_out, int out_size, void* d_ws, size_t ws_size,
                              hipStream_t stream)
{
    // inputs: 0 query, 1 reference_points, 2 value, 3 spatial_shapes(int32),
    // 4 W_value, 5 b_value, 6 W_off, 7 b_off, 8 W_attn, 9 b_attn, 10 W_out, 11 b_out, 12 zeta
    char* ws = (char*)d_ws;
    ushort_t* vproj   = (ushort_t*)ws;                                   // [8][NTOK][32] bf16
    float*    oa      = (float*)(ws + (long)NE * 2);                     // NTOK*384 f32
    ushort_t* q_bf    = (ushort_t*)(ws + (long)NE * 2 + (long)NTOK * 1536);
    ushort_t* outpre  = q_bf;           // overlay: q dead after fused gemm
    ushort_t* v_bf    = q_bf + NE;
    ushort_t* Wv_bf   = v_bf + NE;
    ushort_t* WoWa_bf = Wv_bf + 65536;  // 384 rows: W_off(256) + W_attn(128)
    ushort_t* Wout_bf = WoWa_bf + 98304;

    cvt_k<<<1024, 256, 0, stream>>>(
        (const float*)d_in[0], (const float*)d_in[2], (const float*)d_in[4],
        (const float*)d_in[6], (const float*)d_in[8], (const float*)d_in[10],
        q_bf, v_bf, Wv_bf, WoWa_bf, Wout_bf);

    gemm_fused_k<<<dim3(1248, 1, 2), 256, 0, stream>>>(
        q_bf, v_bf, Wv_bf, WoWa_bf,
        (const float*)d_in[5], (const float*)d_in[7], (const float*)d_in[9],
        (const float*)d_in[12], vproj, oa);

    sample_k<<<8 * 3324, 512, 0, stream>>>(
        (const float*)d_in[1], vproj, oa, outpre);   // outpre overlays q_bf (dead)

    gemm_out_k<<<832, 256, 0, stream>>>(
        outpre, Wout_bf, (const float*)d_in[11], (float*)d_out);
}

// Round 5
// 222.914 us; speedup vs baseline: 1.0922x; 1.0922x over previous
//
#include <hip/hip_runtime.h>

// SparseMSDeformableAttention MI355X — round 13.
// r12 post-mortem: head-pinning WON memory-side (FETCH 111->36.6MB, gathers
// L2-resident) but the no-LDS rewrite LOST compute-side: x4 redundant
// softmax/weights per g-lane + 64-op reduce tree -> VALUBusy 83%, 108us.
//  - sample_k r13: keep head-pinned blocks (h = bid&7 = XCD), restore r11's
//    two-phase split: block = (head, 32 tokens); phase1 = 1 thread per (tok,pt),
//    weights computed ONCE -> skewed LDS (r11-validated, 0 conflicts); phase2 =
//    16 thr/token (s4 x g4), 4 pts/thread, 16x 16B L2-hit gathers, 2-rd reduce.
//  - GEMMs unchanged (r10/r12 body).

#define LQ    13294
#define NTOK  26588
#define NE    6806528     // NTOK*256

typedef unsigned short ushort_t;
typedef __attribute__((ext_vector_type(8))) short short8;
typedef __attribute__((ext_vector_type(8))) unsigned short ushort8_t;
typedef __attribute__((ext_vector_type(4))) float float4_t;

__device__ __forceinline__ ushort_t f2b(float f) {
    unsigned int x = __float_as_uint(f);
    return (ushort_t)((x + 0x7fffu + ((x >> 16) & 1u)) >> 16);   // RNE
}

__device__ __forceinline__ void gload16(const void* g, void* l) {
    __builtin_amdgcn_global_load_lds(
        (const __attribute__((address_space(1))) unsigned int*)g,
        (__attribute__((address_space(3))) unsigned int*)l, 16, 0, 0);
}

// ---------------- bulk f32 -> bf16 convert ----------------
__device__ __forceinline__ void cvt_seg(const float* __restrict__ s,
                                        ushort_t* __restrict__ d,
                                        int n4, int gid, int stride) {
    const float4_t* s4 = (const float4_t*)s;
    for (int i = gid; i < n4; i += stride) {
        float4_t f = s4[i];
        ushort4 o;
        o.x = f2b(f.x); o.y = f2b(f.y); o.z = f2b(f.z); o.w = f2b(f.w);
        *(ushort4*)(d + (long)i * 4) = o;
    }
}

__global__ __launch_bounds__(256) void cvt_k(
    const float* q, const float* v, const float* Wv, const float* Wo,
    const float* Wa, const float* Wout,
    ushort_t* q_bf, ushort_t* v_bf, ushort_t* Wv_bf, ushort_t* WoWa_bf,
    ushort_t* Wout_bf)
{
    const int gid = blockIdx.x * 256 + threadIdx.x;
    const int stride = gridDim.x * 256;
    cvt_seg(q,    q_bf,            NE / 4,     gid, stride);
    cvt_seg(v,    v_bf,            NE / 4,     gid, stride);
    cvt_seg(Wv,   Wv_bf,           65536 / 4,  gid, stride);
    cvt_seg(Wo,   WoWa_bf,         65536 / 4,  gid, stride);   // rows 0..255
    cvt_seg(Wa,   WoWa_bf + 65536, 32768 / 4,  gid, stride);   // rows 256..383
    cvt_seg(Wout, Wout_bf,         65536 / 4,  gid, stride);
}

// ---------------- bf16 MFMA tile body (r10 structure: 12KB LDS, high TLP) ------
// 256 threads = 4 waves; tile 128(M) x 64(N), K-tile 32; LDS linear stride 32.
// Frag maps (r7-validated): A[m=ln&15][k=(ln>>4)*8+j]; B=W[n=ln&15][k];
// D col=ln&15 (n), row=(ln>>4)*4+r (m).
__device__ __forceinline__ void gemm_tile(
    const ushort_t* __restrict__ A,     // [>=m0+128][256] bf16 (OOB rows ok: ws)
    const ushort_t* __restrict__ W,     // [>=n0+64][256] bf16
    int m0, int n0,
    ushort_t* As, ushort_t* Bs, float4_t acc[2][4])
{
    const int tid = threadIdx.x;
    const int w  = tid >> 6;
    const int ln = tid & 63;
    const int lr = ln >> 2;             // row 0..15 within 16-row group
    const int lc = (ln & 3) * 8;        // ushort col {0,8,16,24}

    ushort_t* lA0 = As + (w * 2 + 0) * 512;         // rows w*32 + 0..15
    ushort_t* lA1 = As + (w * 2 + 1) * 512;         // rows w*32 + 16..31
    ushort_t* lB  = Bs + w * 512;                   // rows w*16 + 0..15
    const ushort_t* gA0 = A + (long)(m0 + w * 32 + lr) * 256 + lc;
    const ushort_t* gA1 = gA0 + 16 * 256;
    const ushort_t* gB  = W + (long)(n0 + w * 16 + lr) * 256 + lc;

    const int krow = (ln >> 4) * 8;
    const int fr   = ln & 15;

    for (int k0 = 0; k0 < 256; k0 += 32) {
        gload16(gA0 + k0, lA0);
        gload16(gA1 + k0, lA1);
        gload16(gB  + k0, lB);
        __syncthreads();

        short8 af[2], bfr[4];
        #pragma unroll
        for (int i = 0; i < 2; i++)
            af[i] = *(const short8*)(As + (w * 32 + i * 16 + fr) * 32 + krow);
        #pragma unroll
        for (int j = 0; j < 4; j++)
            bfr[j] = *(const short8*)(Bs + (j * 16 + fr) * 32 + krow);
        #pragma unroll
        for (int i = 0; i < 2; i++)
            #pragma unroll
            for (int j = 0; j < 4; j++)
                acc[i][j] = __builtin_amdgcn_mfma_f32_16x16x32_bf16(af[i], bfr[j], acc[i][j], 0, 0, 0);
        __syncthreads();
    }
}

// ---------------- fused gemm1 (z=0) + gemm2/3 (z=1) ----------------
// z=0: vproj(bf16,*zeta, HEAD-MAJOR [8][NTOK][32]) = v_bf @ Wv^T + b_value
// z=1: oa(f32)[NTOK][384] = q_bf @ [Wo;Wa]^T + [b_off;b_attn]
__global__ __launch_bounds__(256) void gemm_fused_k(
    const ushort_t* __restrict__ q_bf, const ushort_t* __restrict__ v_bf,
    const ushort_t* __restrict__ Wv,   const ushort_t* __restrict__ WoWa,
    const float* __restrict__ b_value, const float* __restrict__ b_off,
    const float* __restrict__ b_attn,  const float* __restrict__ zeta,
    ushort_t* __restrict__ vproj, float* __restrict__ oa)
{
    __shared__ __align__(16) ushort_t As[128 * 32];
    __shared__ __align__(16) ushort_t Bs[64 * 32];

    const int z = blockIdx.z;
    const int bid = blockIdx.x;
    int x, y;
    if (z == 0) {
        if (bid >= 832) return;                 // whole block, before any barrier
        int id = (bid & 7) * 104 + (bid >> 3);  // 832 = 8*104, bijective
        x = id >> 2; y = id & 3;
    } else {
        int id = (bid & 7) * 156 + (bid >> 3);  // 1248 = 8*156, bijective
        x = id / 6; y = id - x * 6;
    }
    const int m0 = x * 128;
    const int n0 = y * 64;

    float4_t acc[2][4] = {};
    gemm_tile(z ? q_bf : v_bf, z ? WoWa : Wv, m0, n0, As, Bs, acc);

    const int tid = threadIdx.x;
    const int w = tid >> 6, ln = tid & 63;
    const int col = ln & 15;
    const int rq  = (ln >> 4) * 4;
    #pragma unroll
    for (int j = 0; j < 4; j++) {
        int n = n0 + j * 16 + col;
        if (z == 0) {
            float bz = b_value[n];
            float zz = zeta[n & 31];
            long hbase = (long)(n >> 5) * NTOK;
            #pragma unroll
            for (int i = 0; i < 2; i++) {
                #pragma unroll
                for (int r = 0; r < 4; r++) {
                    int m = m0 + w * 32 + i * 16 + rq + r;
                    if (m < NTOK)
                        vproj[(hbase + m) * 32 + (n & 31)] = f2b((acc[i][j][r] + bz) * zz);
                }
            }
        } else {
            float bz = (n < 256) ? b_off[n] : b_attn[n - 256];
            #pragma unroll
            for (int i = 0; i < 2; i++) {
                #pragma unroll
                for (int r = 0; r < 4; r++) {
                    int m = m0 + w * 32 + i * 16 + rq + r;
                    if (m < NTOK) oa[(long)m * 384 + n] = acc[i][j][r] + bz;
                }
            }
        }
    }
}

// ---------------- final out-projection gemm (f32 out) ----------------
__global__ __launch_bounds__(256) void gemm_out_k(
    const ushort_t* __restrict__ A,     // outpre [NTOK][256] bf16
    const ushort_t* __restrict__ W,     // Wout_bf [256][256]
    const float* __restrict__ bias,     // [256]
    float* __restrict__ C)              // [NTOK][256] f32
{
    __shared__ __align__(16) ushort_t As[128 * 32];
    __shared__ __align__(16) ushort_t Bs[64 * 32];

    const int bid = blockIdx.x;                 // 832
    int id = (bid & 7) * 104 + (bid >> 3);
    const int m0 = (id >> 2) * 128;
    const int n0 = (id & 3) * 64;

    float4_t acc[2][4] = {};
    gemm_tile(A, W, m0, n0, As, Bs, acc);

    const int tid = threadIdx.x;
    const int w = tid >> 6, ln = tid & 63;
    const int col = ln & 15;
    const int rq  = (ln >> 4) * 4;
    #pragma unroll
    for (int j = 0; j < 4; j++) {
        int n = n0 + j * 16 + col;
        float bz = bias[n];
        #pragma unroll
        for (int i = 0; i < 2; i++) {
            #pragma unroll
            for (int r = 0; r < 4; r++) {
                int m = m0 + w * 32 + i * 16 + rq + r;
                if (m < NTOK) C[(long)m * 256 + n] = acc[i][j][r] + bz;
            }
        }
    }
}

// ---------------- sampler: head-pinned x two-phase ----------------
// Block = (head = bid&7 = XCD, 32 tokens); 512 threads.
// Phase 1: thread = (tok,point): softmax over 16 pts via shfl_xor(1,2,4,8);
//   masked bilinear weights + full byte offsets (head-major vproj) -> skewed LDS.
// Phase 2: 16 thr/token (s(4) x g(4)): 4 pts/thread, 16x 16B L2-hit gathers,
//   shfl_down(8,4) reduce over s; lanes s==0 store 16B.
__global__ __launch_bounds__(512) void sample_k(
    const float* __restrict__ refp,    // [NTOK][4][2]
    const ushort_t* __restrict__ v,    // [8][NTOK][32] bf16 head-major
    const float* __restrict__ oa,      // [NTOK][384]: 256 off then 128 logits
    ushort_t* __restrict__ outp)       // [NTOK][256] bf16
{
    __shared__ __align__(16) int   p_ofs[576][4];   // skewed: su = u + (u>>3)
    __shared__ __align__(16) float p_w[576][4];
    const int bid = blockIdx.x;
    const int h   = bid & 7;                         // head == XCD
    const int tbase = (bid >> 3) * 32;
    const int tid = threadIdx.x;

    {   // ---- phase 1: thread = (tok1, p) ----
        const int tok1 = tid >> 4, p = tid & 15;
        const long t = tbase + tok1;
        if (t < NTOK) {
            const int lvl = p >> 2;
            const int Wi  = (lvl == 0) ? 100 : (lvl == 1) ? 50 : (lvl == 2) ? 25 : 13;
            const int st  = (lvl == 0) ? 0 : (lvl == 1) ? 10000 : (lvl == 2) ? 12500 : 13125;
            const float Wf = (float)Wi;
            const int b = (t >= LQ) ? 1 : 0;

            float lg = oa[t * 384 + 256 + h * 16 + p];
            float smax = lg;
            #pragma unroll
            for (int d = 1; d < 16; d <<= 1) smax = fmaxf(smax, __shfl_xor(smax, d, 64));
            float ex = __expf(lg - smax);
            float sm = ex;
            #pragma unroll
            for (int d = 1; d < 16; d <<= 1) sm += __shfl_xor(sm, d, 64);
            const float a = ex / sm;

            float ox = oa[t * 384 + h * 32 + p * 2];
            float oy = oa[t * 384 + h * 32 + p * 2 + 1];
            float rx = refp[t * 8 + lvl * 2];
            float ry = refp[t * 8 + lvl * 2 + 1];

            float x = rx * Wf + ox - 0.5f;
            float y = ry * Wf + oy - 0.5f;
            float xf = floorf(x), yf = floorf(y);
            float wx = x - xf, wy = y - yf;
            int x0 = (int)xf, y0 = (int)yf;

            float mx0 = ((unsigned)x0       < (unsigned)Wi) ? (1.f - wx) : 0.f;
            float mx1 = ((unsigned)(x0 + 1) < (unsigned)Wi) ? wx         : 0.f;
            float my0 = ((unsigned)y0       < (unsigned)Wi) ? (1.f - wy) * a : 0.f;
            float my1 = ((unsigned)(y0 + 1) < (unsigned)Wi) ? wy * a         : 0.f;
            int x0c = min(max(x0, 0), Wi - 1);
            int x1c = min(max(x0 + 1, 0), Wi - 1);
            int y0c = min(max(y0, 0), Wi - 1);
            int y1c = min(max(y0 + 1, 0), Wi - 1);

            // full byte offsets into head-major vproj [8][NTOK][32] (64B rows)
            const int hb = h * NTOK + b * LQ + st;
            const int r0 = hb + y0c * Wi, r1 = hb + y1c * Wi;
            const int su = tid + (tid >> 3);
            p_ofs[su][0] = (r0 + x0c) << 6;
            p_ofs[su][1] = (r0 + x1c) << 6;
            p_ofs[su][2] = (r1 + x0c) << 6;
            p_ofs[su][3] = (r1 + x1c) << 6;
            p_w[su][0] = mx0 * my0;
            p_w[su][1] = mx1 * my0;
            p_w[su][2] = mx0 * my1;
            p_w[su][3] = mx1 * my1;
        }
    }
    __syncthreads();

    // ---- phase 2: 16 thr/token, 4 points/thread ----
    const int tok2 = tid >> 4, l16 = tid & 15, s = l16 >> 2, g = l16 & 3;
    const long t = tbase + tok2;
    if (t < NTOK) {
        const char* vb = (const char*)v;
        const unsigned go = g * 16;
        const int ub = tok2 * 16 + s * 4;        // points s*4 .. s*4+3
        float4_t accA = {0.f, 0.f, 0.f, 0.f};
        float4_t accB = {0.f, 0.f, 0.f, 0.f};

        #pragma unroll
        for (int q = 0; q < 4; q++) {
            const int u = ub + q;
            const int su = u + (u >> 3);
            int4     o  = *(const int4*)p_ofs[su];
            float4_t w4 = *(const float4_t*)p_w[su];
            uint4 u00 = *(const uint4*)(vb + (unsigned)(o.x + go));
            uint4 u01 = *(const uint4*)(vb + (unsigned)(o.y + go));
            uint4 u10 = *(const uint4*)(vb + (unsigned)(o.z + go));
            uint4 u11 = *(const uint4*)(vb + (unsigned)(o.w + go));
            #define ACC8(U, WGT) \
                accA[0] += (WGT) * __uint_as_float((U).x << 16); \
                accA[1] += (WGT) * __uint_as_float((U).x & 0xffff0000u); \
                accA[2] += (WGT) * __uint_as_float((U).y << 16); \
                accA[3] += (WGT) * __uint_as_float((U).y & 0xffff0000u); \
                accB[0] += (WGT) * __uint_as_float((U).z << 16); \
                accB[1] += (WGT) * __uint_as_float((U).z & 0xffff0000u); \
                accB[2] += (WGT) * __uint_as_float((U).w << 16); \
                accB[3] += (WGT) * __uint_as_float((U).w & 0xffff0000u);
            ACC8(u00, w4.x)
            ACC8(u01, w4.y)
            ACC8(u10, w4.z)
            ACC8(u11, w4.w)
            #undef ACC8
        }

        // reduce over s (tid bits 2-3): d=8 then d=4
        #pragma unroll
        for (int c = 0; c < 4; c++) {
            accA[c] += __shfl_down(accA[c], 8, 64);
            accB[c] += __shfl_down(accB[c], 8, 64);
        }
        #pragma unroll
        for (int c = 0; c < 4; c++) {
            accA[c] += __shfl_down(accA[c], 4, 64);
            accB[c] += __shfl_down(accB[c], 4, 64);
        }

        if (s == 0) {
            ushort8_t o8;
            o8[0] = f2b(accA[0]); o8[1] = f2b(accA[1]);
            o8[2] = f2b(accA[2]); o8[3] = f2b(accA[3]);
            o8[4] = f2b(accB[0]); o8[5] = f2b(accB[1]);
            o8[6] = f2b(accB[2]); o8[7] = f2b(accB[3]);
            *(ushort8_t*)(outp + t * 256 + h * 32 + g * 8) = o8;
        }
    }
}

extern "C" void kernel_launch(void* const* d_in, const int* in_sizes, int n_in,
                              void* d_out, int out_size, void* d_ws, size_t ws_size,
                              hipStream_t stream)
{
    // inputs: 0 query, 1 reference_points, 2 value, 3 spatial_shapes(int32),
    // 4 W_value, 5 b_value, 6 W_off, 7 b_off, 8 W_attn, 9 b_attn, 10 W_out, 11 b_out, 12 zeta
    char* ws = (char*)d_ws;
    ushort_t* vproj   = (ushort_t*)ws;                                   // [8][NTOK][32] bf16
    float*    oa      = (float*)(ws + (long)NE * 2);                     // NTOK*384 f32
    ushort_t* q_bf    = (ushort_t*)(ws + (long)NE * 2 + (long)NTOK * 1536);
    ushort_t* outpre  = q_bf;           // overlay: q dead after fused gemm
    ushort_t* v_bf    = q_bf + NE;
    ushort_t* Wv_bf   = v_bf + NE;
    ushort_t* WoWa_bf = Wv_bf + 65536;  // 384 rows: W_off(256) + W_attn(128)
    ushort_t* Wout_bf = WoWa_bf + 98304;

    cvt_k<<<1024, 256, 0, stream>>>(
        (const float*)d_in[0], (const float*)d_in[2], (const float*)d_in[4],
        (const float*)d_in[6], (const float*)d_in[8], (const float*)d_in[10],
        q_bf, v_bf, Wv_bf, WoWa_bf, Wout_bf);

    gemm_fused_k<<<dim3(1248, 1, 2), 256, 0, stream>>>(
        q_bf, v_bf, Wv_bf, WoWa_bf,
        (const float*)d_in[5], (const float*)d_in[7], (const float*)d_in[9],
        (const float*)d_in[12], vproj, oa);

    sample_k<<<8 * 831, 512, 0, stream>>>(
        (const float*)d_in[1], vproj, oa, outpre);   // outpre overlays q_bf (dead)

    gemm_out_k<<<832, 256, 0, stream>>>(
        outpre, Wout_bf, (const float*)d_in[11], (float*)d_out);
}

// Round 6
// 202.524 us; speedup vs baseline: 1.2021x; 1.1007x over previous
//
#include <hip/hip_runtime.h>

// SparseMSDeformableAttention MI355X — round 14.
// r13 post-mortem: sample_k memory side fixed (FETCH 36.6MB, L2-local) but
// VGPR=68 crossed the 64-reg wave-slot cliff (m69: waves/SIMD halve at 64) ->
// occupancy 23% (~1 block/CU), serial gather latency exposed, 74us.
//  - sample_k: __launch_bounds__(512,8) + q-loop unroll 2 -> VGPR<=64,
//    8 waves/SIMD. Structure unchanged (r13 two-phase, head-pinned).
//  - gemm_tile: A+B double-buffer (24KB), next-step gll issued BEFORE current
//    ds_read+MFMA, ONE barrier per k-step (T3-minimum 2-phase). Old loop
//    drained vmcnt0 immediately after issue -> full 900cy exposed per step.

#define LQ    13294
#define NTOK  26588
#define NE    6806528     // NTOK*256

typedef unsigned short ushort_t;
typedef __attribute__((ext_vector_type(8))) short short8;
typedef __attribute__((ext_vector_type(8))) unsigned short ushort8_t;
typedef __attribute__((ext_vector_type(4))) float float4_t;

__device__ __forceinline__ ushort_t f2b(float f) {
    unsigned int x = __float_as_uint(f);
    return (ushort_t)((x + 0x7fffu + ((x >> 16) & 1u)) >> 16);   // RNE
}

__device__ __forceinline__ void gload16(const void* g, void* l) {
    __builtin_amdgcn_global_load_lds(
        (const __attribute__((address_space(1))) unsigned int*)g,
        (__attribute__((address_space(3))) unsigned int*)l, 16, 0, 0);
}

// ---------------- bulk f32 -> bf16 convert ----------------
__device__ __forceinline__ void cvt_seg(const float* __restrict__ s,
                                        ushort_t* __restrict__ d,
                                        int n4, int gid, int stride) {
    const float4_t* s4 = (const float4_t*)s;
    for (int i = gid; i < n4; i += stride) {
        float4_t f = s4[i];
        ushort4 o;
        o.x = f2b(f.x); o.y = f2b(f.y); o.z = f2b(f.z); o.w = f2b(f.w);
        *(ushort4*)(d + (long)i * 4) = o;
    }
}

__global__ __launch_bounds__(256) void cvt_k(
    const float* q, const float* v, const float* Wv, const float* Wo,
    const float* Wa, const float* Wout,
    ushort_t* q_bf, ushort_t* v_bf, ushort_t* Wv_bf, ushort_t* WoWa_bf,
    ushort_t* Wout_bf)
{
    const int gid = blockIdx.x * 256 + threadIdx.x;
    const int stride = gridDim.x * 256;
    cvt_seg(q,    q_bf,            NE / 4,     gid, stride);
    cvt_seg(v,    v_bf,            NE / 4,     gid, stride);
    cvt_seg(Wv,   Wv_bf,           65536 / 4,  gid, stride);
    cvt_seg(Wo,   WoWa_bf,         65536 / 4,  gid, stride);   // rows 0..255
    cvt_seg(Wa,   WoWa_bf + 65536, 32768 / 4,  gid, stride);   // rows 256..383
    cvt_seg(Wout, Wout_bf,         65536 / 4,  gid, stride);
}

// ---------------- bf16 MFMA tile body: dbuf 2-phase, 1 barrier/k-step ----------
// 256 threads = 4 waves; tile 128(M) x 64(N), K-tile 32; LDS linear stride 32.
// Per k-step: issue 3 gll for step k+1 into the OTHER buffer, then ds_read +
// 8 MFMA on current, then ONE __syncthreads (drains vmcnt AFTER compute overlap).
// Frag maps (r7-validated): A[m=ln&15][k=(ln>>4)*8+j]; B=W[n=ln&15][k];
// D col=ln&15 (n), row=(ln>>4)*4+r (m).
__device__ __forceinline__ void gemm_tile(
    const ushort_t* __restrict__ A,     // [>=m0+128][256] bf16 (OOB rows ok: ws)
    const ushort_t* __restrict__ W,     // [>=n0+64][256] bf16
    int m0, int n0,
    ushort_t* As, ushort_t* Bs, float4_t acc[2][4])
{
    const int tid = threadIdx.x;
    const int w  = tid >> 6;
    const int ln = tid & 63;
    const int lr = ln >> 2;             // row 0..15 within 16-row group
    const int lc = (ln & 3) * 8;        // ushort col {0,8,16,24}

    ushort_t* lA0 = As + (w * 2 + 0) * 512;         // rows w*32 + 0..15
    ushort_t* lA1 = As + (w * 2 + 1) * 512;         // rows w*32 + 16..31
    ushort_t* lB  = Bs + w * 512;                   // rows w*16 + 0..15
    const ushort_t* gA0 = A + (long)(m0 + w * 32 + lr) * 256 + lc;
    const ushort_t* gA1 = gA0 + 16 * 256;
    const ushort_t* gB  = W + (long)(n0 + w * 16 + lr) * 256 + lc;

    const int krow = (ln >> 4) * 8;
    const int fr   = ln & 15;

    // prologue: stage k-tile 0 into buffer 0
    gload16(gA0, lA0);
    gload16(gA1, lA1);
    gload16(gB,  lB);
    __syncthreads();

    #pragma unroll
    for (int kt = 0; kt < 8; kt++) {
        const int cur = kt & 1;
        if (kt < 7) {                   // prefetch next k-tile into other buffer
            const int nxt = cur ^ 1;
            gload16(gA0 + (kt + 1) * 32, lA0 + nxt * 4096);
            gload16(gA1 + (kt + 1) * 32, lA1 + nxt * 4096);
            gload16(gB  + (kt + 1) * 32, lB  + nxt * 2048);
        }
        short8 af[2], bfr[4];
        #pragma unroll
        for (int i = 0; i < 2; i++)
            af[i] = *(const short8*)(As + cur * 4096 + (w * 32 + i * 16 + fr) * 32 + krow);
        #pragma unroll
        for (int j = 0; j < 4; j++)
            bfr[j] = *(const short8*)(Bs + cur * 2048 + (j * 16 + fr) * 32 + krow);
        #pragma unroll
        for (int i = 0; i < 2; i++)
            #pragma unroll
            for (int j = 0; j < 4; j++)
                acc[i][j] = __builtin_amdgcn_mfma_f32_16x16x32_bf16(af[i], bfr[j], acc[i][j], 0, 0, 0);
        __syncthreads();                // drains prefetch + protects cur buffer
    }
}

// ---------------- fused gemm1 (z=0) + gemm2/3 (z=1) ----------------
// z=0: vproj(bf16,*zeta, HEAD-MAJOR [8][NTOK][32]) = v_bf @ Wv^T + b_value
// z=1: oa(f32)[NTOK][384] = q_bf @ [Wo;Wa]^T + [b_off;b_attn]
__global__ __launch_bounds__(256) void gemm_fused_k(
    const ushort_t* __restrict__ q_bf, const ushort_t* __restrict__ v_bf,
    const ushort_t* __restrict__ Wv,   const ushort_t* __restrict__ WoWa,
    const float* __restrict__ b_value, const float* __restrict__ b_off,
    const float* __restrict__ b_attn,  const float* __restrict__ zeta,
    ushort_t* __restrict__ vproj, float* __restrict__ oa)
{
    __shared__ __align__(16) ushort_t As[2 * 4096];
    __shared__ __align__(16) ushort_t Bs[2 * 2048];

    const int z = blockIdx.z;
    const int bid = blockIdx.x;
    int x, y;
    if (z == 0) {
        if (bid >= 832) return;                 // whole block, before any barrier
        int id = (bid & 7) * 104 + (bid >> 3);  // 832 = 8*104, bijective
        x = id >> 2; y = id & 3;
    } else {
        int id = (bid & 7) * 156 + (bid >> 3);  // 1248 = 8*156, bijective
        x = id / 6; y = id - x * 6;
    }
    const int m0 = x * 128;
    const int n0 = y * 64;

    float4_t acc[2][4] = {};
    gemm_tile(z ? q_bf : v_bf, z ? WoWa : Wv, m0, n0, As, Bs, acc);

    const int tid = threadIdx.x;
    const int w = tid >> 6, ln = tid & 63;
    const int col = ln & 15;
    const int rq  = (ln >> 4) * 4;
    #pragma unroll
    for (int j = 0; j < 4; j++) {
        int n = n0 + j * 16 + col;
        if (z == 0) {
            float bz = b_value[n];
            float zz = zeta[n & 31];
            long hbase = (long)(n >> 5) * NTOK;
            #pragma unroll
            for (int i = 0; i < 2; i++) {
                #pragma unroll
                for (int r = 0; r < 4; r++) {
                    int m = m0 + w * 32 + i * 16 + rq + r;
                    if (m < NTOK)
                        vproj[(hbase + m) * 32 + (n & 31)] = f2b((acc[i][j][r] + bz) * zz);
                }
            }
        } else {
            float bz = (n < 256) ? b_off[n] : b_attn[n - 256];
            #pragma unroll
            for (int i = 0; i < 2; i++) {
                #pragma unroll
                for (int r = 0; r < 4; r++) {
                    int m = m0 + w * 32 + i * 16 + rq + r;
                    if (m < NTOK) oa[(long)m * 384 + n] = acc[i][j][r] + bz;
                }
            }
        }
    }
}

// ---------------- final out-projection gemm (f32 out) ----------------
__global__ __launch_bounds__(256) void gemm_out_k(
    const ushort_t* __restrict__ A,     // outpre [NTOK][256] bf16
    const ushort_t* __restrict__ W,     // Wout_bf [256][256]
    const float* __restrict__ bias,     // [256]
    float* __restrict__ C)              // [NTOK][256] f32
{
    __shared__ __align__(16) ushort_t As[2 * 4096];
    __shared__ __align__(16) ushort_t Bs[2 * 2048];

    const int bid = blockIdx.x;                 // 832
    int id = (bid & 7) * 104 + (bid >> 3);
    const int m0 = (id >> 2) * 128;
    const int n0 = (id & 3) * 64;

    float4_t acc[2][4] = {};
    gemm_tile(A, W, m0, n0, As, Bs, acc);

    const int tid = threadIdx.x;
    const int w = tid >> 6, ln = tid & 63;
    const int col = ln & 15;
    const int rq  = (ln >> 4) * 4;
    #pragma unroll
    for (int j = 0; j < 4; j++) {
        int n = n0 + j * 16 + col;
        float bz = bias[n];
        #pragma unroll
        for (int i = 0; i < 2; i++) {
            #pragma unroll
            for (int r = 0; r < 4; r++) {
                int m = m0 + w * 32 + i * 16 + rq + r;
                if (m < NTOK) C[(long)m * 256 + n] = acc[i][j][r] + bz;
            }
        }
    }
}

// ---------------- sampler: head-pinned x two-phase (VGPR<=64) ----------------
// Block = (head = bid&7 = XCD, 32 tokens); 512 threads, 8 waves/SIMD target.
// Phase 1: thread = (tok,point): softmax over 16 pts via shfl_xor(1,2,4,8);
//   masked bilinear weights + full byte offsets (head-major vproj) -> skewed LDS.
// Phase 2: 16 thr/token (s(4) x g(4)): 4 pts/thread in 2 unrolled pairs
//   (8 gathers in flight, not 16 -> fits 64 VGPR), shfl_down(8,4) reduce.
__global__ __launch_bounds__(512, 8) void sample_k(
    const float* __restrict__ refp,    // [NTOK][4][2]
    const ushort_t* __restrict__ v,    // [8][NTOK][32] bf16 head-major
    const float* __restrict__ oa,      // [NTOK][384]: 256 off then 128 logits
    ushort_t* __restrict__ outp)       // [NTOK][256] bf16
{
    __shared__ __align__(16) int   p_ofs[576][4];   // skewed: su = u + (u>>3)
    __shared__ __align__(16) float p_w[576][4];
    const int bid = blockIdx.x;
    const int h   = bid & 7;                         // head == XCD
    const int tbase = (bid >> 3) * 32;
    const int tid = threadIdx.x;

    {   // ---- phase 1: thread = (tok1, p) ----
        const int tok1 = tid >> 4, p = tid & 15;
        const long t = tbase + tok1;
        if (t < NTOK) {
            const int lvl = p >> 2;
            const int Wi  = (lvl == 0) ? 100 : (lvl == 1) ? 50 : (lvl == 2) ? 25 : 13;
            const int st  = (lvl == 0) ? 0 : (lvl == 1) ? 10000 : (lvl == 2) ? 12500 : 13125;
            const float Wf = (float)Wi;
            const int b = (t >= LQ) ? 1 : 0;

            float lg = oa[t * 384 + 256 + h * 16 + p];
            float smax = lg;
            #pragma unroll
            for (int d = 1; d < 16; d <<= 1) smax = fmaxf(smax, __shfl_xor(smax, d, 64));
            float ex = __expf(lg - smax);
            float sm = ex;
            #pragma unroll
            for (int d = 1; d < 16; d <<= 1) sm += __shfl_xor(sm, d, 64);
            const float a = ex / sm;

            float ox = oa[t * 384 + h * 32 + p * 2];
            float oy = oa[t * 384 + h * 32 + p * 2 + 1];
            float rx = refp[t * 8 + lvl * 2];
            float ry = refp[t * 8 + lvl * 2 + 1];

            float x = rx * Wf + ox - 0.5f;
            float y = ry * Wf + oy - 0.5f;
            float xf = floorf(x), yf = floorf(y);
            float wx = x - xf, wy = y - yf;
            int x0 = (int)xf, y0 = (int)yf;

            float mx0 = ((unsigned)x0       < (unsigned)Wi) ? (1.f - wx) : 0.f;
            float mx1 = ((unsigned)(x0 + 1) < (unsigned)Wi) ? wx         : 0.f;
            float my0 = ((unsigned)y0       < (unsigned)Wi) ? (1.f - wy) * a : 0.f;
            float my1 = ((unsigned)(y0 + 1) < (unsigned)Wi) ? wy * a         : 0.f;
            int x0c = min(max(x0, 0), Wi - 1);
            int x1c = min(max(x0 + 1, 0), Wi - 1);
            int y0c = min(max(y0, 0), Wi - 1);
            int y1c = min(max(y0 + 1, 0), Wi - 1);

            // full byte offsets into head-major vproj [8][NTOK][32] (64B rows)
            const int hb = h * NTOK + b * LQ + st;
            const int r0 = hb + y0c * Wi, r1 = hb + y1c * Wi;
            const int su = tid + (tid >> 3);
            p_ofs[su][0] = (r0 + x0c) << 6;
            p_ofs[su][1] = (r0 + x1c) << 6;
            p_ofs[su][2] = (r1 + x0c) << 6;
            p_ofs[su][3] = (r1 + x1c) << 6;
            p_w[su][0] = mx0 * my0;
            p_w[su][1] = mx1 * my0;
            p_w[su][2] = mx0 * my1;
            p_w[su][3] = mx1 * my1;
        }
    }
    __syncthreads();

    // ---- phase 2: 16 thr/token, 4 points/thread (2 unrolled pairs) ----
    const int tok2 = tid >> 4, l16 = tid & 15, s = l16 >> 2, g = l16 & 3;
    const long t = tbase + tok2;
    if (t < NTOK) {
        const char* vb = (const char*)v;
        const unsigned go = g * 16;
        const int ub = tok2 * 16 + s * 4;        // points s*4 .. s*4+3
        float4_t accA = {0.f, 0.f, 0.f, 0.f};
        float4_t accB = {0.f, 0.f, 0.f, 0.f};

        #pragma unroll 2
        for (int q = 0; q < 4; q++) {
            const int u = ub + q;
            const int su = u + (u >> 3);
            int4     o  = *(const int4*)p_ofs[su];
            float4_t w4 = *(const float4_t*)p_w[su];
            uint4 u00 = *(const uint4*)(vb + (unsigned)(o.x + go));
            uint4 u01 = *(const uint4*)(vb + (unsigned)(o.y + go));
            uint4 u10 = *(const uint4*)(vb + (unsigned)(o.z + go));
            uint4 u11 = *(const uint4*)(vb + (unsigned)(o.w + go));
            #define ACC8(U, WGT) \
                accA[0] += (WGT) * __uint_as_float((U).x << 16); \
                accA[1] += (WGT) * __uint_as_float((U).x & 0xffff0000u); \
                accA[2] += (WGT) * __uint_as_float((U).y << 16); \
                accA[3] += (WGT) * __uint_as_float((U).y & 0xffff0000u); \
                accB[0] += (WGT) * __uint_as_float((U).z << 16); \
                accB[1] += (WGT) * __uint_as_float((U).z & 0xffff0000u); \
                accB[2] += (WGT) * __uint_as_float((U).w << 16); \
                accB[3] += (WGT) * __uint_as_float((U).w & 0xffff0000u);
            ACC8(u00, w4.x)
            ACC8(u01, w4.y)
            ACC8(u10, w4.z)
            ACC8(u11, w4.w)
            #undef ACC8
        }

        // reduce over s (tid bits 2-3): d=8 then d=4
        #pragma unroll
        for (int c = 0; c < 4; c++) {
            accA[c] += __shfl_down(accA[c], 8, 64);
            accB[c] += __shfl_down(accB[c], 8, 64);
        }
        #pragma unroll
        for (int c = 0; c < 4; c++) {
            accA[c] += __shfl_down(accA[c], 4, 64);
            accB[c] += __shfl_down(accB[c], 4, 64);
        }

        if (s == 0) {
            ushort8_t o8;
            o8[0] = f2b(accA[0]); o8[1] = f2b(accA[1]);
            o8[2] = f2b(accA[2]); o8[3] = f2b(accA[3]);
            o8[4] = f2b(accB[0]); o8[5] = f2b(accB[1]);
            o8[6] = f2b(accB[2]); o8[7] = f2b(accB[3]);
            *(ushort8_t*)(outp + t * 256 + h * 32 + g * 8) = o8;
        }
    }
}

extern "C" void kernel_launch(void* const* d_in, const int* in_sizes, int n_in,
                              void* d_out, int out_size, void* d_ws, size_t ws_size,
                              hipStream_t stream)
{
    // inputs: 0 query, 1 reference_points, 2 value, 3 spatial_shapes(int32),
    // 4 W_value, 5 b_value, 6 W_off, 7 b_off, 8 W_attn, 9 b_attn, 10 W_out, 11 b_out, 12 zeta
    char* ws = (char*)d_ws;
    ushort_t* vproj   = (ushort_t*)ws;                                   // [8][NTOK][32] bf16
    float*    oa      = (float*)(ws + (long)NE * 2);                     // NTOK*384 f32
    ushort_t* q_bf    = (ushort_t*)(ws + (long)NE * 2 + (long)NTOK * 1536);
    ushort_t* outpre  = q_bf;           // overlay: q dead after fused gemm
    ushort_t* v_bf    = q_bf + NE;
    ushort_t* Wv_bf   = v_bf + NE;
    ushort_t* WoWa_bf = Wv_bf + 65536;  // 384 rows: W_off(256) + W_attn(128)
    ushort_t* Wout_bf = WoWa_bf + 98304;

    cvt_k<<<2048, 256, 0, stream>>>(
        (const float*)d_in[0], (const float*)d_in[2], (const float*)d_in[4],
        (const float*)d_in[6], (const float*)d_in[8], (const float*)d_in[10],
        q_bf, v_bf, Wv_bf, WoWa_bf, Wout_bf);

    gemm_fused_k<<<dim3(1248, 1, 2), 256, 0, stream>>>(
        q_bf, v_bf, Wv_bf, WoWa_bf,
        (const float*)d_in[5], (const float*)d_in[7], (const float*)d_in[9],
        (const float*)d_in[12], vproj, oa);

    sample_k<<<8 * 831, 512, 0, stream>>>(
        (const float*)d_in[1], vproj, oa, outpre);   // outpre overlays q_bf (dead)

    gemm_out_k<<<832, 256, 0, stream>>>(
        outpre, Wout_bf, (const float*)d_in[11], (float*)d_out);
}